// Round 7
// baseline (1001.612 us; speedup 1.0000x reference)
//
#include <hip/hip_runtime.h>
#include <type_traits>

#define N_NODES 50000
#define N_EDGES 400000
#define R_DIM   32
#define F_DIM   132
#define EV_DIM  15
#define F_Q     33
#define INT_DIM 135
#define TE      32      // edges per block in K_a
#define NPB     32      // nodes per block in node_proj

#define RCP_NORM_INV 0.17407765595569785f  // 1/sqrt(33)
#define RCP_NORM_EV  0.15075567228888181f  // 1/sqrt(44)

typedef __attribute__((ext_vector_type(8))) short bf16x8;
typedef __attribute__((ext_vector_type(4))) float f32x4;

__device__ __forceinline__ float silu_f(float x) {
    // x * rcp(1+exp(-x)): v_rcp_f32 instead of full-precision divide (~6 VALU saved)
    return x * __builtin_amdgcn_rcpf(1.f + __expf(-x));
}

__device__ __forceinline__ unsigned short f2bf(float x) {
    union { float f; unsigned u; } c; c.f = x;
    unsigned r = c.u + 0x7FFFu + ((c.u >> 16) & 1u);  // RNE
    return (unsigned short)(r >> 16);
}

__device__ __forceinline__ float bf2f(unsigned short x) {
    union { unsigned u; float f; } c; c.u = (unsigned)x << 16;
    return c.f;
}

// ---------------------------------------------------------------------------
// prep_w2: layer-2 weights -> MFMA b-frag order (bf16), K=192 combined.
// ---------------------------------------------------------------------------
__global__ __launch_bounds__(256) void prep_w2_kernel(
    const float* __restrict__ fi_rW2, const float* __restrict__ fi_eW2,
    const float* __restrict__ fe_rW2, const float* __restrict__ fe_eW2,
    const float* __restrict__ fi_rb2, const float* __restrict__ fi_eb2,
    const float* __restrict__ fe_rb2, const float* __restrict__ fe_eb2,
    unsigned short* __restrict__ Bfrag, float* __restrict__ biasC)
{
    int t = blockIdx.x * 256 + threadIdx.x;
    if (t < 6912) {
        int l = t & 63, idx = t >> 6;
        int nt = idx % 9, kc = (idx / 9) % 6, f = idx / 54;
        const float* rW2 = f ? fe_rW2 : fi_rW2;
        const float* eW2 = f ? fe_eW2 : fi_eW2;
        int n = nt * 16 + (l & 15);
        unsigned short v[8];
        #pragma unroll
        for (int j = 0; j < 8; ++j) {
            int k = kc * 32 + (l >> 4) * 8 + j;
            float w = 0.f;
            if (n < F_DIM) {
                if (k < F_DIM) w = rW2[k * F_DIM + n];
                else if (k < F_DIM + F_Q) w = eW2[(k - F_DIM) * F_DIM + n];
            }
            v[j] = f2bf(w);
        }
        *(uint4*)&Bfrag[(size_t)t * 8] = *(const uint4*)v;
    }
    if (blockIdx.x == 0) {
        for (int i = threadIdx.x; i < 288; i += 256) {
            int f = i / 144, n = i % 144;
            const float* rb2 = f ? fe_rb2 : fi_rb2;
            const float* eb2 = f ? fe_eb2 : fi_eb2;
            biasC[i] = (n < F_DIM) ? (rb2[n] + eb2[n]) : 0.f;
        }
    }
}

// ---------------------------------------------------------------------------
// prep_aux: edge layer-1 b-frags + biasB1 + node-proj b-frags (Bnp).
// Bnp blocks: Qi 0-23, Ki 24-47, Vi 48-71 (4h x 2kc x 3nt), Qe 72-89, Ke 90-107.
// ---------------------------------------------------------------------------
__global__ __launch_bounds__(256) void prep_aux_kernel(
    const float* __restrict__ fi_rW1, const float* __restrict__ fe_rW1,
    const float* __restrict__ fi_rb1, const float* __restrict__ fi_eb1,
    const float* __restrict__ fe_rb1, const float* __restrict__ fe_eb1,
    const float* __restrict__ Wq_inv, const float* __restrict__ Wk_inv,
    const float* __restrict__ Wv_inv,
    const float* __restrict__ Wq_ev, const float* __restrict__ Wk_ev,
    unsigned short* __restrict__ B1frag, float* __restrict__ biasB1,
    unsigned short* __restrict__ Bnp)
{
    int t = blockIdx.x * 256 + threadIdx.x;
    if (t < 1536) {
        int l = t & 63, idx = t >> 6;     // idx = f*12 + nt
        int nt = idx % 12, f = idx / 12;
        const float* rW1 = f ? fe_rW1 : fi_rW1;
        int n = nt * 16 + (l & 15);
        unsigned short v[8];
        #pragma unroll
        for (int j = 0; j < 8; ++j) {
            int k = (l >> 4) * 8 + j;
            float w = (n < F_DIM) ? rW1[k * F_DIM + n] : 0.f;
            v[j] = f2bf(w);
        }
        *(uint4*)&B1frag[(size_t)t * 8] = *(const uint4*)v;
    } else if (t < 1920) {
        int i = t - 1536;
        int f = i / 192, n = i % 192;
        const float* rb1 = f ? fe_rb1 : fi_rb1;
        const float* eb1 = f ? fe_eb1 : fi_eb1;
        biasB1[i] = (n < F_DIM) ? rb1[n] : ((n < 165) ? eb1[n - F_DIM] : 0.f);
    } else if (t < 1920 + 6912) {
        int u = t - 1920;
        int l = u & 63, blk = u >> 6;
        int n = 0; const float* W = nullptr; int D = 0, h = 0, kc = 0;
        if (blk < 72) {
            int arr = blk / 24, wb = blk % 24;
            h = wb / 6; kc = (wb % 6) / 3; int nt = wb % 3;
            W = (arr == 0) ? Wq_inv : (arr == 1) ? Wk_inv : Wv_inv;
            D = 33; n = nt * 16 + (l & 15);
            W += h * 1089;
        } else {
            int b2 = blk - 72;
            int which = b2 / 18, wb = b2 % 18;
            h = wb / 6; kc = (wb % 6) / 3; int nt = wb % 3;
            W = which ? Wk_ev : Wq_ev;
            D = 44; n = nt * 16 + (l & 15);
            W += h * 1936;
        }
        unsigned short v[8];
        #pragma unroll
        for (int j = 0; j < 8; ++j) {
            int k = kc * 32 + (l >> 4) * 8 + j;
            float w = (k < D && n < D) ? W[k * D + n] : 0.f;
            v[j] = f2bf(w);
        }
        *(uint4*)&Bnp[(size_t)u * 8] = *(const uint4*)v;
    }
}

// ---------------------------------------------------------------------------
// CSR build: histogram -> coalesced 3-phase scan -> scatter permutation
// ---------------------------------------------------------------------------
__global__ __launch_bounds__(256) void hist_kernel(
    const int* __restrict__ receivers, int* __restrict__ cnt)
{
    int i = blockIdx.x * 256 + threadIdx.x;
    if (i < N_EDGES) atomicAdd(&cnt[receivers[i]], 1);
}

__global__ __launch_bounds__(1024) void scan_tile_sum(
    const int* __restrict__ cnt, int* __restrict__ tsum)
{
    int idx = blockIdx.x * 1024 + threadIdx.x;
    int v = (idx < N_NODES) ? cnt[idx] : 0;
    for (int o = 32; o > 0; o >>= 1) v += __shfl_down(v, o);
    __shared__ int wsum[16];
    if ((threadIdx.x & 63) == 0) wsum[threadIdx.x >> 6] = v;
    __syncthreads();
    if (threadIdx.x == 0) {
        int s = 0;
        for (int i = 0; i < 16; ++i) s += wsum[i];
        tsum[blockIdx.x] = s;
    }
}

__global__ __launch_bounds__(64) void scan_base(
    const int* __restrict__ tsum, int* __restrict__ tbase)
{
    if (threadIdx.x == 0) {
        int run = 0;
        for (int i = 0; i < 49; ++i) { tbase[i] = run; run += tsum[i]; }
    }
}

__global__ __launch_bounds__(1024) void scan_tile(
    const int* __restrict__ cnt, const int* __restrict__ tbase,
    int* __restrict__ off, int* __restrict__ cursor)
{
    __shared__ int s[1024];
    int t = threadIdx.x;
    int idx = blockIdx.x * 1024 + t;
    int v = (idx < N_NODES) ? cnt[idx] : 0;
    s[t] = v;
    __syncthreads();
    for (int d = 1; d < 1024; d <<= 1) {
        int x = (t >= d) ? s[t - d] : 0;
        __syncthreads();
        s[t] += x;
        __syncthreads();
    }
    int o = tbase[blockIdx.x] + s[t] - v;
    if (idx < N_NODES) { off[idx] = o; cursor[idx] = o; }
    if (idx == 0) off[N_NODES] = N_EDGES;
}

__global__ __launch_bounds__(256) void scatter_kernel(
    const int* __restrict__ receivers, int* __restrict__ cursor,
    int* __restrict__ perm)
{
    int i = blockIdx.x * 256 + threadIdx.x;
    if (i < N_EDGES) {
        int pos = atomicAdd(&cursor[receivers[i]], 1);
        perm[pos] = i;
    }
}

// ---------------------------------------------------------------------------
// Kernel 1: node projections via MFMA. 32 nodes/block, 4 waves.
// q/k/v outputs stored bf16 (halves random-gather lines downstream).
// ---------------------------------------------------------------------------
__global__ __launch_bounds__(256) void node_proj_kernel(
    const float* __restrict__ x,
    const unsigned short* __restrict__ Bnp,
    unsigned short* __restrict__ q_inv, unsigned short* __restrict__ k_inv,
    unsigned short* __restrict__ v_bf,
    unsigned short* __restrict__ q_ev, unsigned short* __restrict__ k_ev)
{
    __shared__ __align__(16) unsigned short sx[NPB][456];
    const int node0 = blockIdx.x * NPB;
    const int tid = threadIdx.x;
    for (int i = tid; i < NPB * 448; i += 256) {
        int nd = i / 448, t = i % 448;
        int seg = t >> 6, d = t & 63;
        float v = 0.f;
        int gn = node0 + nd;
        if (gn < N_NODES) {
            if (seg < 4) { if (d < 33) v = x[(size_t)gn * F_DIM + seg * 33 + d]; }
            else         { int h = seg - 4; if (d < 44) v = x[(size_t)gn * F_DIM + h * 44 + d]; }
        }
        sx[nd][t] = f2bf(v);
    }
    __syncthreads();
    const int wv = tid >> 6, l = tid & 63, l15 = l & 15, g4 = l >> 4;
    const int half = wv & 1, m0 = (wv >> 1) * 16;
    const unsigned short* arow = &sx[m0 + l15][0];
    const unsigned short* Bl = Bnp + (size_t)l * 8;

    auto do_inv = [&](int arr, unsigned short* __restrict__ out, bool dosilu) {
        const unsigned short* Ba = Bl + (size_t)arr * 24 * 512;
        #pragma unroll
        for (int h = 0; h < 4; ++h) {
            bf16x8 a0 = *(const bf16x8*)&arow[h * 64 + g4 * 8];
            bf16x8 a1 = *(const bf16x8*)&arow[h * 64 + 32 + g4 * 8];
            #pragma unroll
            for (int nt = 0; nt < 3; ++nt) {
                f32x4 c = {0.f, 0.f, 0.f, 0.f};
                c = __builtin_amdgcn_mfma_f32_16x16x32_bf16(
                        a0, *(const bf16x8*)(Ba + (size_t)((h * 2 + 0) * 3 + nt) * 512), c, 0, 0, 0);
                c = __builtin_amdgcn_mfma_f32_16x16x32_bf16(
                        a1, *(const bf16x8*)(Ba + (size_t)((h * 2 + 1) * 3 + nt) * 512), c, 0, 0, 0);
                int e = nt * 16 + l15;
                if (e < 33) {
                    #pragma unroll
                    for (int r = 0; r < 4; ++r) {
                        int gn = node0 + m0 + g4 * 4 + r;
                        if (gn < N_NODES) {
                            float v = c[r];
                            if (dosilu) v = silu_f(v);
                            out[(size_t)gn * F_DIM + h * 33 + e] = f2bf(v);
                        }
                    }
                }
            }
        }
    };
    auto do_ev = [&](int which, unsigned short* __restrict__ out) {
        const unsigned short* Ba = Bl + (size_t)(72 + which * 18) * 512;
        #pragma unroll
        for (int h = 0; h < 3; ++h) {
            bf16x8 a0 = *(const bf16x8*)&arow[256 + h * 64 + g4 * 8];
            bf16x8 a1 = *(const bf16x8*)&arow[256 + h * 64 + 32 + g4 * 8];
            #pragma unroll
            for (int nt = 0; nt < 3; ++nt) {
                f32x4 c = {0.f, 0.f, 0.f, 0.f};
                c = __builtin_amdgcn_mfma_f32_16x16x32_bf16(
                        a0, *(const bf16x8*)(Ba + (size_t)((h * 2 + 0) * 3 + nt) * 512), c, 0, 0, 0);
                c = __builtin_amdgcn_mfma_f32_16x16x32_bf16(
                        a1, *(const bf16x8*)(Ba + (size_t)((h * 2 + 1) * 3 + nt) * 512), c, 0, 0, 0);
                int e = nt * 16 + l15;
                if (e < 44) {
                    #pragma unroll
                    for (int r = 0; r < 4; ++r) {
                        int gn = node0 + m0 + g4 * 4 + r;
                        if (gn < N_NODES)
                            out[(size_t)gn * F_DIM + h * 44 + e] = f2bf(silu_f(c[r]));
                    }
                }
            }
        }
    };
    if (half == 0) { do_inv(0, q_inv, true); do_inv(1, k_inv, true); }
    else           { do_inv(2, v_bf, false); do_ev(0, q_ev); do_ev(1, k_ev); }
}

// ---------------------------------------------------------------------------
// K_a: edge filters (both layers MFMA) + alpha + FUSED per-receiver
// aggregation (phase V replaces the old gather_kernel). alpha stays in LDS.
// CSR-sorted blocks: complete receiver-groups use plain stores; only
// block-boundary groups use atomicAdd (a_inv/a_ev pre-zeroed).
// ---------------------------------------------------------------------------
__global__ __launch_bounds__(256) void edge_alpha_kernel(
    const float* __restrict__ ev_feat, const float* __restrict__ rbf,
    const float* __restrict__ cutoffs, const float* __restrict__ sh_vec,
    const int* __restrict__ senders, const int* __restrict__ receivers,
    const int* __restrict__ perm, const int* __restrict__ off,
    const float* __restrict__ fi_eW1, const float* __restrict__ fe_eW1,
    const unsigned short* __restrict__ B1frag, const float* __restrict__ biasB1,
    const unsigned short* __restrict__ Bfrag, const float* __restrict__ biasC,
    const unsigned short* __restrict__ q_inv, const unsigned short* __restrict__ k_inv,
    const unsigned short* __restrict__ q_ev, const unsigned short* __restrict__ k_ev,
    const unsigned short* __restrict__ v_bf,
    float* __restrict__ a_inv, float* __restrict__ a_ev)
{
    __shared__ __align__(16) unsigned short s_hid[2][TE][200];
    __shared__ __align__(16) unsigned short s_ain[TE][40];
    __shared__ float s_d2[TE][16];
    __shared__ float s_ei[3][TE];
    __shared__ float s_c[TE];
    __shared__ float s_alpha[TE][8];
    __shared__ int s_snd[TE], s_rcv[TE], s_eid[TE];
    __shared__ unsigned char s_glast[TE], s_gcomp[TE];

    const int e0g = blockIdx.x * TE;
    const int tid = threadIdx.x;

    // ---- P0a: edge meta via CSR perm
    if (tid < TE) {
        int eid = perm[e0g + tid];
        s_eid[tid] = eid;
        int sn = senders[eid], rc = receivers[eid];
        s_snd[tid] = sn; s_rcv[tid] = rc;
        s_c[tid] = cutoffs[eid];
    }
    __syncthreads();
    // ---- P0b: rbf -> bf16 LDS rows; ev_diff^2
    for (int i = tid; i < TE * R_DIM; i += 256) {
        int e = i >> 5, k = i & 31;
        s_ain[e][k] = f2bf(rbf[(size_t)s_eid[e] * R_DIM + k]);
    }
    for (int i = tid; i < TE * EV_DIM; i += 256) {
        int e = i / EV_DIM, j = i - e * EV_DIM;
        float d = ev_feat[(size_t)s_snd[e] * EV_DIM + j]
                - ev_feat[(size_t)s_rcv[e] * EV_DIM + j];
        s_d2[e][j] = d * d;
    }
    __syncthreads();
    if (tid < TE * 3) {
        int e = tid / 3, k2 = tid - e * 3;
        int i0 = (k2 == 0) ? 0 : (k2 == 1) ? 3 : 8;
        int i1 = (k2 == 0) ? 3 : (k2 == 1) ? 8 : 15;
        float s = 0.f;
        for (int i = i0; i < i1; ++i) s += s_d2[e][i];
        s_ei[k2][e] = s;
    } else if (tid < TE * 3 + TE) {
        // group metadata for phase V
        int e = tid - TE * 3;
        int rcv = s_rcv[e];
        s_glast[e] = (e == TE - 1) || (s_rcv[e + 1] != rcv);
        s_gcomp[e] = (off[rcv] >= e0g) && (off[rcv + 1] <= e0g + TE);
    }
    __syncthreads();

    const int wv = tid >> 6, l = tid & 63;
    const int f = wv & 1, m0 = (wv >> 1) * 16;
    const int l15 = l & 15, g4 = l >> 4;

    int rcvr[4], sndr[4];
    #pragma unroll
    for (int r = 0; r < 4; ++r) {
        int e = m0 + g4 * 4 + r;
        rcvr[r] = s_rcv[e]; sndr[r] = s_snd[e];
    }

    // ---- P1: layer 1 via MFMA (K=32); ev-branch as rank-3 epilogue.
    {
        bf16x8 a1 = *(const bf16x8*)&s_ain[m0 + l15][g4 * 8];
        const unsigned short* B1f = B1frag + (size_t)f * 6144 + (size_t)l * 8;
        const float* eW1f = f ? fe_eW1 : fi_eW1;
        #pragma unroll
        for (int nt = 0; nt < 12; ++nt) {
            f32x4 c = {0.f, 0.f, 0.f, 0.f};
            bf16x8 b1 = *(const bf16x8*)(B1f + (size_t)nt * 512);
            c = __builtin_amdgcn_mfma_f32_16x16x32_bf16(a1, b1, c, 0, 0, 0);
            const int n = nt * 16 + l15;
            const float bias = biasB1[f * 192 + n];
            float w0 = 0.f, w1 = 0.f, w2 = 0.f;
            if (n >= F_DIM && n < 165) {
                w0 = eW1f[n - F_DIM];
                w1 = eW1f[F_Q + n - F_DIM];
                w2 = eW1f[2 * F_Q + n - F_DIM];
            }
            #pragma unroll
            for (int r = 0; r < 4; ++r) {
                int e = m0 + g4 * 4 + r;
                float eic = w0 * s_ei[0][e] + w1 * s_ei[1][e] + w2 * s_ei[2][e];
                float v = silu_f(c[r] + bias + eic);
                s_hid[f][e][n] = f2bf(v);
            }
        }
    }

    // ---- P2: layer-2 MFMA (K=192) + pipelined q/k gathers + alpha -> LDS
    bf16x8 afr[6];
    {
        const unsigned short* hrow = &s_hid[f][m0 + l15][0];
        #pragma unroll
        for (int kc = 0; kc < 6; ++kc)
            afr[kc] = *(const bf16x8*)&hrow[kc * 32 + g4 * 8];
    }
    const unsigned short* Bf = Bfrag + (size_t)f * 54 * 512 + (size_t)l * 8;

    auto run = [&](auto FC) {
        constexpr int F_ = decltype(FC)::value;
        constexpr int NH = F_ ? 3 : 4;
        constexpr int DD = F_ ? 44 : 33;
        const unsigned short* qp = F_ ? q_ev : q_inv;
        const unsigned short* kp = F_ ? k_ev : k_inv;
        float part[NH][4];
        #pragma unroll
        for (int h = 0; h < NH; ++h)
            #pragma unroll
            for (int r = 0; r < 4; ++r) part[h][r] = 0.f;

        auto ldtile = [&](int nt, float (&bq)[4], float (&bk)[4]) {
            const int n = nt * 16 + l15;
            #pragma unroll
            for (int r = 0; r < 4; ++r) {
                float qv = 0.f, kv = 0.f;
                if (n < F_DIM) {
                    qv = bf2f(qp[(size_t)rcvr[r] * F_DIM + n]);
                    kv = bf2f(kp[(size_t)sndr[r] * F_DIM + n]);
                }
                bq[r] = qv; bk[r] = kv;
            }
        };

        float bq[2][4], bk[2][4];
        ldtile(0, bq[0], bk[0]);
        ldtile(1, bq[1], bk[1]);

        #pragma unroll
        for (int nt = 0; nt < 9; ++nt) {
            float cq[4], ck[4];
            #pragma unroll
            for (int r = 0; r < 4; ++r) { cq[r] = bq[nt & 1][r]; ck[r] = bk[nt & 1][r]; }
            if (nt + 2 < 9) ldtile(nt + 2, bq[nt & 1], bk[nt & 1]);

            f32x4 acc = {0.f, 0.f, 0.f, 0.f};
            #pragma unroll
            for (int kc = 0; kc < 6; ++kc) {
                bf16x8 bfr = *(const bf16x8*)(Bf + (size_t)(kc * 9 + nt) * 512);
                acc = __builtin_amdgcn_mfma_f32_16x16x32_bf16(afr[kc], bfr, acc, 0, 0, 0);
            }
            const int n = nt * 16 + l15;
            const bool nvalid = (n < F_DIM);
            const float bias = biasC[F_ * 144 + n];
            int h0v = (nt * 16) / DD;
            int bsp = (h0v + 1) * DD - nt * 16;
            #pragma unroll
            for (int r = 0; r < 4; ++r) {
                float p = 0.f;
                if (nvalid) p = (acc[r] + bias) * cq[r] * ck[r];
                if (bsp >= 16) {
                    part[h0v][r] += p;
                } else {
                    float plo = (l15 < bsp) ? p : 0.f;
                    part[h0v][r] += plo;
                    if (h0v + 1 < NH) part[h0v + 1][r] += (p - plo);
                }
            }
        }
        #pragma unroll
        for (int h = 0; h < NH; ++h) {
            #pragma unroll
            for (int r = 0; r < 4; ++r) {
                float v = part[h][r];
                v += __shfl_xor(v, 1);
                v += __shfl_xor(v, 2);
                v += __shfl_xor(v, 4);
                v += __shfl_xor(v, 8);
                if (l15 == 0) {
                    int e = m0 + g4 * 4 + r;
                    s_alpha[e][F_ ? 4 + h : h] =
                        v * s_c[e] * (F_ ? RCP_NORM_EV : RCP_NORM_INV);
                }
            }
        }
    };
    if (f == 0) run(std::integral_constant<int, 0>{});
    else        run(std::integral_constant<int, 1>{});

    __syncthreads();   // all alphas in LDS

    // ---- Phase V: fused per-receiver aggregation (was gather_kernel).
    // Threads 0..131: inv cols (coalesced bf16 v rows); 132..146: ev cols.
    if (tid < F_DIM) {
        const int c = tid;
        const int h = c / 33;
        float acc = 0.f;
        #pragma unroll 4
        for (int e = 0; e < TE; ++e) {
            float vv = bf2f(v_bf[(size_t)s_snd[e] * F_DIM + c]);
            acc += s_alpha[e][h] * vv;
            if (s_glast[e]) {
                float* dst = &a_inv[(size_t)s_rcv[e] * F_DIM + c];
                if (s_gcomp[e]) *dst = acc;
                else atomicAdd(dst, acc);
                acc = 0.f;
            }
        }
    } else if (tid < F_DIM + EV_DIM) {
        const int j = tid - F_DIM;
        const int seg = (j < 3) ? 0 : (j < 8) ? 1 : 2;
        float acc = 0.f;
        #pragma unroll 4
        for (int e = 0; e < TE; ++e) {
            float sv = sh_vec[(size_t)s_eid[e] * EV_DIM + j];
            acc += s_alpha[e][4 + seg] * sv;
            if (s_glast[e]) {
                float* dst = &a_ev[(size_t)s_rcv[e] * EV_DIM + j];
                if (s_gcomp[e]) *dst = acc;
                else atomicAdd(dst, acc);
                acc = 0.f;
            }
        }
    }
}

// ---------------------------------------------------------------------------
// Kernel 3: epilogue — residuals, 135x135 interaction, outputs. 16 nodes/block.
// ---------------------------------------------------------------------------
__global__ __launch_bounds__(256) void epilogue_kernel(
    const float* __restrict__ inv_feat, const float* __restrict__ ev_feat,
    const float* __restrict__ acc_inv, const float* __restrict__ acc_ev,
    const float* __restrict__ W_int, const float* __restrict__ b_int,
    float* __restrict__ out0, float* __restrict__ out1)
{
    const int NB = 16;
    __shared__ float s_in[NB][INT_DIM + 1];
    __shared__ float s_ev1[NB][EV_DIM + 1];
    __shared__ float s_b[NB][3];
    int n0 = blockIdx.x * NB;
    int tid = threadIdx.x;
    for (int i = tid; i < NB * F_DIM; i += 256) {
        int nb = i / F_DIM, j = i - nb * F_DIM;
        size_t idx = (size_t)(n0 + nb) * F_DIM + j;
        s_in[nb][j] = inv_feat[idx] + acc_inv[idx];
    }
    for (int i = tid; i < NB * EV_DIM; i += 256) {
        int nb = i / EV_DIM, j = i - nb * EV_DIM;
        size_t idx = (size_t)(n0 + nb) * EV_DIM + j;
        s_ev1[nb][j] = ev_feat[idx] + acc_ev[idx];
    }
    __syncthreads();
    if (tid < NB * 3) {
        int nb = tid / 3, k = tid - nb * 3;
        int i0 = (k == 0) ? 0 : (k == 1) ? 3 : 8;
        int i1 = (k == 0) ? 3 : (k == 1) ? 8 : 15;
        float s = 0.f;
        for (int i = i0; i < i1; ++i) { float v = s_ev1[nb][i]; s += v * v; }
        s_in[nb][F_DIM + k] = s;
    }
    __syncthreads();
    if (tid < INT_DIM) {
        int j = tid;
        float b = b_int[j];
        float acc[NB];
        #pragma unroll
        for (int nb = 0; nb < NB; ++nb) acc[nb] = b;
        for (int i = 0; i < INT_DIM; ++i) {
            float w = W_int[i * INT_DIM + j];
            #pragma unroll
            for (int nb = 0; nb < NB; ++nb) acc[nb] += s_in[nb][i] * w;
        }
        if (j < F_DIM) {
            #pragma unroll
            for (int nb = 0; nb < NB; ++nb)
                out0[(size_t)(n0 + nb) * F_DIM + j] = s_in[nb][j] + acc[nb];
        } else {
            #pragma unroll
            for (int nb = 0; nb < NB; ++nb)
                s_b[nb][j - F_DIM] = acc[nb];
        }
    }
    __syncthreads();
    for (int i = tid; i < NB * EV_DIM; i += 256) {
        int nb = i / EV_DIM, ii = i - nb * EV_DIM;
        int seg = (ii < 3) ? 0 : (ii < 8) ? 1 : 2;
        out1[(size_t)(n0 + nb) * EV_DIM + ii] = s_ev1[nb][ii] * (1.f + s_b[nb][seg]);
    }
}

// ---------------------------------------------------------------------------
extern "C" void kernel_launch(void* const* d_in, const int* in_sizes, int n_in,
                              void* d_out, int out_size, void* d_ws, size_t ws_size,
                              hipStream_t stream)
{
    const float* inv_feat  = (const float*)d_in[0];
    const float* ev_feat   = (const float*)d_in[1];
    const float* rbf       = (const float*)d_in[2];
    const float* sh_vec    = (const float*)d_in[3];
    const float* cutoffs   = (const float*)d_in[4];
    const int*   senders   = (const int*)d_in[5];
    const int*   receivers = (const int*)d_in[6];
    const float* Wq_inv = (const float*)d_in[7];
    const float* Wk_inv = (const float*)d_in[8];
    const float* Wv_inv = (const float*)d_in[9];
    const float* Wq_ev  = (const float*)d_in[10];
    const float* Wk_ev  = (const float*)d_in[11];
    const float* fi_rW1 = (const float*)d_in[12];
    const float* fi_rb1 = (const float*)d_in[13];
    const float* fi_rW2 = (const float*)d_in[14];
    const float* fi_rb2 = (const float*)d_in[15];
    const float* fi_eW1 = (const float*)d_in[16];
    const float* fi_eb1 = (const float*)d_in[17];
    const float* fi_eW2 = (const float*)d_in[18];
    const float* fi_eb2 = (const float*)d_in[19];
    const float* fe_rW1 = (const float*)d_in[20];
    const float* fe_rb1 = (const float*)d_in[21];
    const float* fe_rW2 = (const float*)d_in[22];
    const float* fe_rb2 = (const float*)d_in[23];
    const float* fe_eW1 = (const float*)d_in[24];
    const float* fe_eb1 = (const float*)d_in[25];
    const float* fe_eW2 = (const float*)d_in[26];
    const float* fe_eb2 = (const float*)d_in[27];
    const float* W_int  = (const float*)d_in[28];
    const float* b_int  = (const float*)d_in[29];

    const size_t NF = (size_t)N_NODES * F_DIM;
    const size_t NE = (size_t)N_NODES * EV_DIM;
    float* ws    = (float*)d_ws;
    float* a_inv = ws;                          // NF f32 (zeroed)
    float* a_ev  = ws + NF;                     // NE f32 (zeroed, contiguous)
    int*   perm   = (int*)(a_ev + NE);
    int*   cnt    = perm + N_EDGES;
    int*   off    = cnt + N_NODES;
    int*   cursor = off + (N_NODES + 4);
    unsigned short* Bfrag  = (unsigned short*)(cursor + N_NODES);
    float*          biasC  = (float*)(Bfrag + 55296);
    unsigned short* B1frag = (unsigned short*)(biasC + 288);
    float*          biasB1 = (float*)(B1frag + 12288);
    unsigned short* Bnp    = (unsigned short*)(biasB1 + 384);
    int* tsum  = (int*)(Bnp + 55296);
    int* tbase = tsum + 64;
    unsigned short* q_inv = (unsigned short*)(tbase + 64);  // NF bf16 each
    unsigned short* k_inv = q_inv + NF;
    unsigned short* q_ev  = k_inv + NF;
    unsigned short* k_ev  = q_ev + NF;
    unsigned short* v_bf  = k_ev + NF;

    float* out0 = (float*)d_out;
    float* out1 = out0 + NF;

    hipMemsetAsync(cnt, 0, N_NODES * sizeof(int), stream);
    hipMemsetAsync(a_inv, 0, (NF + NE) * sizeof(float), stream);
    hist_kernel<<<(N_EDGES + 255) / 256, 256, 0, stream>>>(receivers, cnt);
    scan_tile_sum<<<49, 1024, 0, stream>>>(cnt, tsum);
    scan_base<<<1, 64, 0, stream>>>(tsum, tbase);
    scan_tile<<<49, 1024, 0, stream>>>(cnt, tbase, off, cursor);
    scatter_kernel<<<(N_EDGES + 255) / 256, 256, 0, stream>>>(receivers, cursor, perm);

    prep_w2_kernel<<<27, 256, 0, stream>>>(
        fi_rW2, fi_eW2, fe_rW2, fe_eW2,
        fi_rb2, fi_eb2, fe_rb2, fe_eb2, Bfrag, biasC);

    prep_aux_kernel<<<35, 256, 0, stream>>>(
        fi_rW1, fe_rW1, fi_rb1, fi_eb1, fe_rb1, fe_eb1,
        Wq_inv, Wk_inv, Wv_inv, Wq_ev, Wk_ev,
        B1frag, biasB1, Bnp);

    node_proj_kernel<<<(N_NODES + NPB - 1) / NPB, 256, 0, stream>>>(
        inv_feat, Bnp, q_inv, k_inv, v_bf, q_ev, k_ev);

    edge_alpha_kernel<<<N_EDGES / TE, 256, 0, stream>>>(
        ev_feat, rbf, cutoffs, sh_vec, senders, receivers, perm, off,
        fi_eW1, fe_eW1, B1frag, biasB1, Bfrag, biasC,
        q_inv, k_inv, q_ev, k_ev, v_bf,
        a_inv, a_ev);

    epilogue_kernel<<<N_NODES / 16, 256, 0, stream>>>(
        inv_feat, ev_feat, a_inv, a_ev, W_int, b_int, out0, out1);
}

// Round 8
// 720.045 us; speedup vs baseline: 1.3910x; 1.3910x over previous
//
#include <hip/hip_runtime.h>
#include <type_traits>

#define N_NODES 50000
#define N_EDGES 400000
#define R_DIM   32
#define F_DIM   132
#define EV_DIM  15
#define F_Q     33
#define INT_DIM 135
#define TE      32      // edges per block in K_a
#define NPB     32      // nodes per block in node_proj

#define RCP_NORM_INV 0.17407765595569785f  // 1/sqrt(33)
#define RCP_NORM_EV  0.15075567228888181f  // 1/sqrt(44)

typedef __attribute__((ext_vector_type(8))) short bf16x8;
typedef __attribute__((ext_vector_type(4))) float f32x4;

__device__ __forceinline__ float silu_f(float x) {
    return x * __builtin_amdgcn_rcpf(1.f + __expf(-x));
}

__device__ __forceinline__ unsigned short f2bf(float x) {
    union { float f; unsigned u; } c; c.f = x;
    unsigned r = c.u + 0x7FFFu + ((c.u >> 16) & 1u);  // RNE
    return (unsigned short)(r >> 16);
}

__device__ __forceinline__ float bf2f(unsigned short x) {
    union { unsigned u; float f; } c; c.u = (unsigned)x << 16;
    return c.f;
}

// ---------------------------------------------------------------------------
// prep_w2: layer-2 weights -> MFMA b-frag order (bf16), K=192 combined.
// Extended: also preps W_int (135x135) into b-frag order for the epilogue
// (9 n-tiles x 5 k-chunks, K padded to 160).
// ---------------------------------------------------------------------------
__global__ __launch_bounds__(256) void prep_w2_kernel(
    const float* __restrict__ fi_rW2, const float* __restrict__ fi_eW2,
    const float* __restrict__ fe_rW2, const float* __restrict__ fe_eW2,
    const float* __restrict__ fi_rb2, const float* __restrict__ fi_eb2,
    const float* __restrict__ fe_rb2, const float* __restrict__ fe_eb2,
    const float* __restrict__ W_int,
    unsigned short* __restrict__ Bfrag, float* __restrict__ biasC,
    unsigned short* __restrict__ Wfrag_int)
{
    int t = blockIdx.x * 256 + threadIdx.x;
    if (t < 6912) {
        int l = t & 63, idx = t >> 6;
        int nt = idx % 9, kc = (idx / 9) % 6, f = idx / 54;
        const float* rW2 = f ? fe_rW2 : fi_rW2;
        const float* eW2 = f ? fe_eW2 : fi_eW2;
        int n = nt * 16 + (l & 15);
        unsigned short v[8];
        #pragma unroll
        for (int j = 0; j < 8; ++j) {
            int k = kc * 32 + (l >> 4) * 8 + j;
            float w = 0.f;
            if (n < F_DIM) {
                if (k < F_DIM) w = rW2[k * F_DIM + n];
                else if (k < F_DIM + F_Q) w = eW2[(k - F_DIM) * F_DIM + n];
            }
            v[j] = f2bf(w);
        }
        *(uint4*)&Bfrag[(size_t)t * 8] = *(const uint4*)v;
    } else if (t < 6912 + 2880) {
        int u = t - 6912;
        int l = u & 63, idx = u >> 6;
        int nt = idx % 9, kc = idx / 9;
        int n = nt * 16 + (l & 15);
        unsigned short v[8];
        #pragma unroll
        for (int j = 0; j < 8; ++j) {
            int k = kc * 32 + (l >> 4) * 8 + j;
            float w = (k < INT_DIM && n < INT_DIM) ? W_int[k * INT_DIM + n] : 0.f;
            v[j] = f2bf(w);
        }
        *(uint4*)&Wfrag_int[(size_t)u * 8] = *(const uint4*)v;
    }
    if (blockIdx.x == 0) {
        for (int i = threadIdx.x; i < 288; i += 256) {
            int f = i / 144, n = i % 144;
            const float* rb2 = f ? fe_rb2 : fi_rb2;
            const float* eb2 = f ? fe_eb2 : fi_eb2;
            biasC[i] = (n < F_DIM) ? (rb2[n] + eb2[n]) : 0.f;
        }
    }
}

// ---------------------------------------------------------------------------
// prep_aux: edge layer-1 b-frags + biasB1 + node-proj b-frags (Bnp).
// Bnp blocks: Qi 0-23, Ki 24-47, Vi 48-71 (4h x 2kc x 3nt), Qe 72-89, Ke 90-107.
// ---------------------------------------------------------------------------
__global__ __launch_bounds__(256) void prep_aux_kernel(
    const float* __restrict__ fi_rW1, const float* __restrict__ fe_rW1,
    const float* __restrict__ fi_rb1, const float* __restrict__ fi_eb1,
    const float* __restrict__ fe_rb1, const float* __restrict__ fe_eb1,
    const float* __restrict__ Wq_inv, const float* __restrict__ Wk_inv,
    const float* __restrict__ Wv_inv,
    const float* __restrict__ Wq_ev, const float* __restrict__ Wk_ev,
    unsigned short* __restrict__ B1frag, float* __restrict__ biasB1,
    unsigned short* __restrict__ Bnp)
{
    int t = blockIdx.x * 256 + threadIdx.x;
    if (t < 1536) {
        int l = t & 63, idx = t >> 6;     // idx = f*12 + nt
        int nt = idx % 12, f = idx / 12;
        const float* rW1 = f ? fe_rW1 : fi_rW1;
        int n = nt * 16 + (l & 15);
        unsigned short v[8];
        #pragma unroll
        for (int j = 0; j < 8; ++j) {
            int k = (l >> 4) * 8 + j;
            float w = (n < F_DIM) ? rW1[k * F_DIM + n] : 0.f;
            v[j] = f2bf(w);
        }
        *(uint4*)&B1frag[(size_t)t * 8] = *(const uint4*)v;
    } else if (t < 1920) {
        int i = t - 1536;
        int f = i / 192, n = i % 192;
        const float* rb1 = f ? fe_rb1 : fi_rb1;
        const float* eb1 = f ? fe_eb1 : fi_eb1;
        biasB1[i] = (n < F_DIM) ? rb1[n] : ((n < 165) ? eb1[n - F_DIM] : 0.f);
    } else if (t < 1920 + 6912) {
        int u = t - 1920;
        int l = u & 63, blk = u >> 6;
        int n = 0; const float* W = nullptr; int D = 0, h = 0, kc = 0;
        if (blk < 72) {
            int arr = blk / 24, wb = blk % 24;
            h = wb / 6; kc = (wb % 6) / 3; int nt = wb % 3;
            W = (arr == 0) ? Wq_inv : (arr == 1) ? Wk_inv : Wv_inv;
            D = 33; n = nt * 16 + (l & 15);
            W += h * 1089;
        } else {
            int b2 = blk - 72;
            int which = b2 / 18, wb = b2 % 18;
            h = wb / 6; kc = (wb % 6) / 3; int nt = wb % 3;
            W = which ? Wk_ev : Wq_ev;
            D = 44; n = nt * 16 + (l & 15);
            W += h * 1936;
        }
        unsigned short v[8];
        #pragma unroll
        for (int j = 0; j < 8; ++j) {
            int k = kc * 32 + (l >> 4) * 8 + j;
            float w = (k < D && n < D) ? W[k * D + n] : 0.f;
            v[j] = f2bf(w);
        }
        *(uint4*)&Bnp[(size_t)u * 8] = *(const uint4*)v;
    }
}

// ---------------------------------------------------------------------------
// CSR build: histogram -> coalesced 3-phase scan -> scatter permutation
// ---------------------------------------------------------------------------
__global__ __launch_bounds__(256) void hist_kernel(
    const int* __restrict__ receivers, int* __restrict__ cnt)
{
    int i = blockIdx.x * 256 + threadIdx.x;
    if (i < N_EDGES) atomicAdd(&cnt[receivers[i]], 1);
}

__global__ __launch_bounds__(1024) void scan_tile_sum(
    const int* __restrict__ cnt, int* __restrict__ tsum)
{
    int idx = blockIdx.x * 1024 + threadIdx.x;
    int v = (idx < N_NODES) ? cnt[idx] : 0;
    for (int o = 32; o > 0; o >>= 1) v += __shfl_down(v, o);
    __shared__ int wsum[16];
    if ((threadIdx.x & 63) == 0) wsum[threadIdx.x >> 6] = v;
    __syncthreads();
    if (threadIdx.x == 0) {
        int s = 0;
        for (int i = 0; i < 16; ++i) s += wsum[i];
        tsum[blockIdx.x] = s;
    }
}

__global__ __launch_bounds__(64) void scan_base(
    const int* __restrict__ tsum, int* __restrict__ tbase)
{
    if (threadIdx.x == 0) {
        int run = 0;
        for (int i = 0; i < 49; ++i) { tbase[i] = run; run += tsum[i]; }
    }
}

__global__ __launch_bounds__(1024) void scan_tile(
    const int* __restrict__ cnt, const int* __restrict__ tbase,
    int* __restrict__ off, int* __restrict__ cursor)
{
    __shared__ int s[1024];
    int t = threadIdx.x;
    int idx = blockIdx.x * 1024 + t;
    int v = (idx < N_NODES) ? cnt[idx] : 0;
    s[t] = v;
    __syncthreads();
    for (int d = 1; d < 1024; d <<= 1) {
        int x = (t >= d) ? s[t - d] : 0;
        __syncthreads();
        s[t] += x;
        __syncthreads();
    }
    int o = tbase[blockIdx.x] + s[t] - v;
    if (idx < N_NODES) { off[idx] = o; cursor[idx] = o; }
    if (idx == 0) off[N_NODES] = N_EDGES;
}

__global__ __launch_bounds__(256) void scatter_kernel(
    const int* __restrict__ receivers, int* __restrict__ cursor,
    int* __restrict__ perm)
{
    int i = blockIdx.x * 256 + threadIdx.x;
    if (i < N_EDGES) {
        int pos = atomicAdd(&cursor[receivers[i]], 1);
        perm[pos] = i;
    }
}

// ---------------------------------------------------------------------------
// Kernel 1: node projections via MFMA. 32 nodes/block, 4 waves.
// q/k/v outputs stored bf16.
// ---------------------------------------------------------------------------
__global__ __launch_bounds__(256) void node_proj_kernel(
    const float* __restrict__ x,
    const unsigned short* __restrict__ Bnp,
    unsigned short* __restrict__ q_inv, unsigned short* __restrict__ k_inv,
    unsigned short* __restrict__ v_bf,
    unsigned short* __restrict__ q_ev, unsigned short* __restrict__ k_ev)
{
    __shared__ __align__(16) unsigned short sx[NPB][456];
    const int node0 = blockIdx.x * NPB;
    const int tid = threadIdx.x;
    for (int i = tid; i < NPB * 448; i += 256) {
        int nd = i / 448, t = i % 448;
        int seg = t >> 6, d = t & 63;
        float v = 0.f;
        int gn = node0 + nd;
        if (gn < N_NODES) {
            if (seg < 4) { if (d < 33) v = x[(size_t)gn * F_DIM + seg * 33 + d]; }
            else         { int h = seg - 4; if (d < 44) v = x[(size_t)gn * F_DIM + h * 44 + d]; }
        }
        sx[nd][t] = f2bf(v);
    }
    __syncthreads();
    const int wv = tid >> 6, l = tid & 63, l15 = l & 15, g4 = l >> 4;
    const int half = wv & 1, m0 = (wv >> 1) * 16;
    const unsigned short* arow = &sx[m0 + l15][0];
    const unsigned short* Bl = Bnp + (size_t)l * 8;

    auto do_inv = [&](int arr, unsigned short* __restrict__ out, bool dosilu) {
        const unsigned short* Ba = Bl + (size_t)arr * 24 * 512;
        #pragma unroll
        for (int h = 0; h < 4; ++h) {
            bf16x8 a0 = *(const bf16x8*)&arow[h * 64 + g4 * 8];
            bf16x8 a1 = *(const bf16x8*)&arow[h * 64 + 32 + g4 * 8];
            #pragma unroll
            for (int nt = 0; nt < 3; ++nt) {
                f32x4 c = {0.f, 0.f, 0.f, 0.f};
                c = __builtin_amdgcn_mfma_f32_16x16x32_bf16(
                        a0, *(const bf16x8*)(Ba + (size_t)((h * 2 + 0) * 3 + nt) * 512), c, 0, 0, 0);
                c = __builtin_amdgcn_mfma_f32_16x16x32_bf16(
                        a1, *(const bf16x8*)(Ba + (size_t)((h * 2 + 1) * 3 + nt) * 512), c, 0, 0, 0);
                int e = nt * 16 + l15;
                if (e < 33) {
                    #pragma unroll
                    for (int r = 0; r < 4; ++r) {
                        int gn = node0 + m0 + g4 * 4 + r;
                        if (gn < N_NODES) {
                            float v = c[r];
                            if (dosilu) v = silu_f(v);
                            out[(size_t)gn * F_DIM + h * 33 + e] = f2bf(v);
                        }
                    }
                }
            }
        }
    };
    auto do_ev = [&](int which, unsigned short* __restrict__ out) {
        const unsigned short* Ba = Bl + (size_t)(72 + which * 18) * 512;
        #pragma unroll
        for (int h = 0; h < 3; ++h) {
            bf16x8 a0 = *(const bf16x8*)&arow[256 + h * 64 + g4 * 8];
            bf16x8 a1 = *(const bf16x8*)&arow[256 + h * 64 + 32 + g4 * 8];
            #pragma unroll
            for (int nt = 0; nt < 3; ++nt) {
                f32x4 c = {0.f, 0.f, 0.f, 0.f};
                c = __builtin_amdgcn_mfma_f32_16x16x32_bf16(
                        a0, *(const bf16x8*)(Ba + (size_t)((h * 2 + 0) * 3 + nt) * 512), c, 0, 0, 0);
                c = __builtin_amdgcn_mfma_f32_16x16x32_bf16(
                        a1, *(const bf16x8*)(Ba + (size_t)((h * 2 + 1) * 3 + nt) * 512), c, 0, 0, 0);
                int e = nt * 16 + l15;
                if (e < 44) {
                    #pragma unroll
                    for (int r = 0; r < 4; ++r) {
                        int gn = node0 + m0 + g4 * 4 + r;
                        if (gn < N_NODES)
                            out[(size_t)gn * F_DIM + h * 44 + e] = f2bf(silu_f(c[r]));
                    }
                }
            }
        }
    };
    if (half == 0) { do_inv(0, q_inv, true); do_inv(1, k_inv, true); }
    else           { do_inv(2, v_bf, false); do_ev(0, q_ev); do_ev(1, k_ev); }
}

// ---------------------------------------------------------------------------
// K_a: edge filters (both layers MFMA) + alpha. R4-proven structure:
// q/k gathers (bf16) depth-2 pipelined inside P2.
// ---------------------------------------------------------------------------
__global__ __launch_bounds__(256) void edge_alpha_kernel(
    const float* __restrict__ ev_feat, const float* __restrict__ rbf,
    const float* __restrict__ cutoffs,
    const int* __restrict__ senders, const int* __restrict__ receivers,
    const int* __restrict__ perm,
    const float* __restrict__ fi_eW1, const float* __restrict__ fe_eW1,
    const unsigned short* __restrict__ B1frag, const float* __restrict__ biasB1,
    const unsigned short* __restrict__ Bfrag, const float* __restrict__ biasC,
    const unsigned short* __restrict__ q_inv, const unsigned short* __restrict__ k_inv,
    const unsigned short* __restrict__ q_ev, const unsigned short* __restrict__ k_ev,
    float* __restrict__ galpha, int* __restrict__ gsnd)
{
    __shared__ __align__(16) unsigned short s_hid[2][TE][200];
    __shared__ __align__(16) unsigned short s_ain[TE][40];
    __shared__ float s_d2[TE][16];
    __shared__ float s_ei[3][TE];
    __shared__ float s_c[TE];
    __shared__ int s_snd[TE], s_rcv[TE], s_eid[TE];

    const int e0g = blockIdx.x * TE;
    const int tid = threadIdx.x;

    // ---- P0a: edge meta via CSR perm
    if (tid < TE) {
        int eid = perm[e0g + tid];
        s_eid[tid] = eid;
        int sn = senders[eid], rc = receivers[eid];
        s_snd[tid] = sn; s_rcv[tid] = rc;
        s_c[tid] = cutoffs[eid];
        gsnd[e0g + tid] = sn;
    }
    __syncthreads();
    // ---- P0b: rbf -> bf16 LDS rows; ev_diff^2
    for (int i = tid; i < TE * R_DIM; i += 256) {
        int e = i >> 5, k = i & 31;
        s_ain[e][k] = f2bf(rbf[(size_t)s_eid[e] * R_DIM + k]);
    }
    for (int i = tid; i < TE * EV_DIM; i += 256) {
        int e = i / EV_DIM, j = i - e * EV_DIM;
        float d = ev_feat[(size_t)s_snd[e] * EV_DIM + j]
                - ev_feat[(size_t)s_rcv[e] * EV_DIM + j];
        s_d2[e][j] = d * d;
    }
    __syncthreads();
    if (tid < TE * 3) {
        int e = tid / 3, k2 = tid - e * 3;
        int i0 = (k2 == 0) ? 0 : (k2 == 1) ? 3 : 8;
        int i1 = (k2 == 0) ? 3 : (k2 == 1) ? 8 : 15;
        float s = 0.f;
        for (int i = i0; i < i1; ++i) s += s_d2[e][i];
        s_ei[k2][e] = s;
    }
    __syncthreads();

    const int wv = tid >> 6, l = tid & 63;
    const int f = wv & 1, m0 = (wv >> 1) * 16;
    const int l15 = l & 15, g4 = l >> 4;

    int rcvr[4], sndr[4];
    #pragma unroll
    for (int r = 0; r < 4; ++r) {
        int e = m0 + g4 * 4 + r;
        rcvr[r] = s_rcv[e]; sndr[r] = s_snd[e];
    }

    // ---- P1: layer 1 via MFMA (K=32); ev-branch as rank-3 epilogue.
    {
        bf16x8 a1 = *(const bf16x8*)&s_ain[m0 + l15][g4 * 8];
        const unsigned short* B1f = B1frag + (size_t)f * 6144 + (size_t)l * 8;
        const float* eW1f = f ? fe_eW1 : fi_eW1;
        #pragma unroll
        for (int nt = 0; nt < 12; ++nt) {
            f32x4 c = {0.f, 0.f, 0.f, 0.f};
            bf16x8 b1 = *(const bf16x8*)(B1f + (size_t)nt * 512);
            c = __builtin_amdgcn_mfma_f32_16x16x32_bf16(a1, b1, c, 0, 0, 0);
            const int n = nt * 16 + l15;
            const float bias = biasB1[f * 192 + n];
            float w0 = 0.f, w1 = 0.f, w2 = 0.f;
            if (n >= F_DIM && n < 165) {
                w0 = eW1f[n - F_DIM];
                w1 = eW1f[F_Q + n - F_DIM];
                w2 = eW1f[2 * F_Q + n - F_DIM];
            }
            #pragma unroll
            for (int r = 0; r < 4; ++r) {
                int e = m0 + g4 * 4 + r;
                float eic = w0 * s_ei[0][e] + w1 * s_ei[1][e] + w2 * s_ei[2][e];
                float v = silu_f(c[r] + bias + eic);
                s_hid[f][e][n] = f2bf(v);
            }
        }
    }

    // ---- P2: layer-2 MFMA (K=192) + pipelined q/k gathers + alpha epilogue
    bf16x8 afr[6];
    {
        const unsigned short* hrow = &s_hid[f][m0 + l15][0];
        #pragma unroll
        for (int kc = 0; kc < 6; ++kc)
            afr[kc] = *(const bf16x8*)&hrow[kc * 32 + g4 * 8];
    }
    const unsigned short* Bf = Bfrag + (size_t)f * 54 * 512 + (size_t)l * 8;

    auto run = [&](auto FC) {
        constexpr int F_ = decltype(FC)::value;
        constexpr int NH = F_ ? 3 : 4;
        constexpr int DD = F_ ? 44 : 33;
        const unsigned short* qp = F_ ? q_ev : q_inv;
        const unsigned short* kp = F_ ? k_ev : k_inv;
        float part[NH][4];
        #pragma unroll
        for (int h = 0; h < NH; ++h)
            #pragma unroll
            for (int r = 0; r < 4; ++r) part[h][r] = 0.f;

        auto ldtile = [&](int nt, float (&bq)[4], float (&bk)[4]) {
            const int n = nt * 16 + l15;
            #pragma unroll
            for (int r = 0; r < 4; ++r) {
                float qv = 0.f, kv = 0.f;
                if (n < F_DIM) {
                    qv = bf2f(qp[(size_t)rcvr[r] * F_DIM + n]);
                    kv = bf2f(kp[(size_t)sndr[r] * F_DIM + n]);
                }
                bq[r] = qv; bk[r] = kv;
            }
        };

        float bq[2][4], bk[2][4];
        ldtile(0, bq[0], bk[0]);
        ldtile(1, bq[1], bk[1]);

        #pragma unroll
        for (int nt = 0; nt < 9; ++nt) {
            float cq[4], ck[4];
            #pragma unroll
            for (int r = 0; r < 4; ++r) { cq[r] = bq[nt & 1][r]; ck[r] = bk[nt & 1][r]; }
            if (nt + 2 < 9) ldtile(nt + 2, bq[nt & 1], bk[nt & 1]);

            f32x4 acc = {0.f, 0.f, 0.f, 0.f};
            #pragma unroll
            for (int kc = 0; kc < 6; ++kc) {
                bf16x8 bfr = *(const bf16x8*)(Bf + (size_t)(kc * 9 + nt) * 512);
                acc = __builtin_amdgcn_mfma_f32_16x16x32_bf16(afr[kc], bfr, acc, 0, 0, 0);
            }
            const int n = nt * 16 + l15;
            const bool nvalid = (n < F_DIM);
            const float bias = biasC[F_ * 144 + n];
            int h0v = (nt * 16) / DD;
            int bsp = (h0v + 1) * DD - nt * 16;
            #pragma unroll
            for (int r = 0; r < 4; ++r) {
                float p = 0.f;
                if (nvalid) p = (acc[r] + bias) * cq[r] * ck[r];
                if (bsp >= 16) {
                    part[h0v][r] += p;
                } else {
                    float plo = (l15 < bsp) ? p : 0.f;
                    part[h0v][r] += plo;
                    if (h0v + 1 < NH) part[h0v + 1][r] += (p - plo);
                }
            }
        }
        #pragma unroll
        for (int h = 0; h < NH; ++h) {
            #pragma unroll
            for (int r = 0; r < 4; ++r) {
                float v = part[h][r];
                v += __shfl_xor(v, 1);
                v += __shfl_xor(v, 2);
                v += __shfl_xor(v, 4);
                v += __shfl_xor(v, 8);
                if (l15 == 0) {
                    int e = m0 + g4 * 4 + r;
                    galpha[(size_t)(e0g + e) * 8 + (F_ ? 4 + h : h)] =
                        v * s_c[e] * (F_ ? RCP_NORM_EV : RCP_NORM_INV);
                }
            }
        }
    };
    if (f == 0) run(std::integral_constant<int, 0>{});
    else        run(std::integral_constant<int, 1>{});
}

// ---------------------------------------------------------------------------
// K_b: node-centric aggregation. 4 nodes/block, 1 wave/node. No atomics.
// v read as bf16 (half the random lines).
// ---------------------------------------------------------------------------
__global__ __launch_bounds__(256) void gather_kernel(
    const unsigned short* __restrict__ v_bf, const float* __restrict__ sh_vec,
    const float* __restrict__ galpha,
    const int* __restrict__ gsnd, const int* __restrict__ perm,
    const int* __restrict__ off,
    float* __restrict__ a_inv, float* __restrict__ a_ev)
{
    int n = blockIdx.x * 4 + (threadIdx.x >> 6);
    int l = threadIdx.x & 63;
    int beg = off[n], end = off[n + 1];
    int c0 = l, c1 = l + 64, c2 = l + 128;
    int h0 = c0 / 33, h1 = c1 / 33;
    float acc0 = 0.f, acc1 = 0.f, acc2 = 0.f, aev = 0.f;
    int seg = (l < 3) ? 0 : (l < 8) ? 1 : 2;
    #pragma unroll 4
    for (int p = beg; p < end; ++p) {
        int snd = gsnd[p];
        const float* ga = &galpha[(size_t)p * 8];
        const unsigned short* vr = &v_bf[(size_t)snd * F_DIM];
        acc0 += ga[h0] * bf2f(vr[c0]);
        acc1 += ga[h1] * bf2f(vr[c1]);
        if (l < 4) acc2 += ga[3] * bf2f(vr[c2]);
        if (l < EV_DIM) {
            int eid = perm[p];
            aev += ga[4 + seg] * sh_vec[(size_t)eid * EV_DIM + l];
        }
    }
    float* dr = &a_inv[(size_t)n * F_DIM];
    dr[c0] = acc0; dr[c1] = acc1;
    if (l < 4) dr[c2] = acc2;
    if (l < EV_DIM) a_ev[(size_t)n * EV_DIM + l] = aev;
}

// ---------------------------------------------------------------------------
// Kernel 3: epilogue — residuals + 135x135 interaction via MFMA.
// 16 nodes/block; [16x160(bf16)] @ Wfrag_int (9 n-tiles x 5 k-chunks).
// ---------------------------------------------------------------------------
__global__ __launch_bounds__(256) void epilogue_kernel(
    const float* __restrict__ inv_feat, const float* __restrict__ ev_feat,
    const float* __restrict__ acc_inv, const float* __restrict__ acc_ev,
    const unsigned short* __restrict__ Wfrag_int, const float* __restrict__ b_int,
    float* __restrict__ out0, float* __restrict__ out1)
{
    const int NB = 16;
    __shared__ float s_in[NB][INT_DIM + 1];
    __shared__ __align__(16) unsigned short s_inb[NB][168]; // 168-stride: bank spread
    __shared__ float s_ev1[NB][EV_DIM + 1];
    __shared__ float s_b[NB][3];
    int n0 = blockIdx.x * NB;
    int tid = threadIdx.x;
    for (int i = tid; i < NB * F_DIM; i += 256) {
        int nb = i / F_DIM, j = i - nb * F_DIM;
        size_t idx = (size_t)(n0 + nb) * F_DIM + j;
        s_in[nb][j] = inv_feat[idx] + acc_inv[idx];
    }
    for (int i = tid; i < NB * EV_DIM; i += 256) {
        int nb = i / EV_DIM, j = i - nb * EV_DIM;
        size_t idx = (size_t)(n0 + nb) * EV_DIM + j;
        s_ev1[nb][j] = ev_feat[idx] + acc_ev[idx];
    }
    __syncthreads();
    if (tid < NB * 3) {
        int nb = tid / 3, k = tid - nb * 3;
        int i0 = (k == 0) ? 0 : (k == 1) ? 3 : 8;
        int i1 = (k == 0) ? 3 : (k == 1) ? 8 : 15;
        float s = 0.f;
        for (int i = i0; i < i1; ++i) { float v = s_ev1[nb][i]; s += v * v; }
        s_in[nb][F_DIM + k] = s;
    }
    __syncthreads();
    // bf16 A-tile (K padded 135->160)
    for (int i = tid; i < NB * 160; i += 256) {
        int nb = i / 160, j = i - nb * 160;
        s_inb[nb][j] = f2bf((j < INT_DIM) ? s_in[nb][j] : 0.f);
    }
    __syncthreads();
    const int wv = tid >> 6, l = tid & 63, l15 = l & 15, g4 = l >> 4;
    for (int nt = wv; nt < 9; nt += 4) {
        f32x4 c = {0.f, 0.f, 0.f, 0.f};
        #pragma unroll
        for (int kc = 0; kc < 5; ++kc) {
            bf16x8 a = *(const bf16x8*)&s_inb[l15][kc * 32 + g4 * 8];
            bf16x8 b = *(const bf16x8*)(Wfrag_int + (size_t)((kc * 9 + nt) * 64 + l) * 8);
            c = __builtin_amdgcn_mfma_f32_16x16x32_bf16(a, b, c, 0, 0, 0);
        }
        int j = nt * 16 + l15;
        float bias = (j < INT_DIM) ? b_int[j] : 0.f;
        #pragma unroll
        for (int r = 0; r < 4; ++r) {
            int nb = g4 * 4 + r;
            float val = c[r] + bias;
            if (j < F_DIM)
                out0[(size_t)(n0 + nb) * F_DIM + j] = s_in[nb][j] + val;
            else if (j < INT_DIM)
                s_b[nb][j - F_DIM] = val;
        }
    }
    __syncthreads();
    for (int i = tid; i < NB * EV_DIM; i += 256) {
        int nb = i / EV_DIM, ii = i - nb * EV_DIM;
        int seg = (ii < 3) ? 0 : (ii < 8) ? 1 : 2;
        out1[(size_t)(n0 + nb) * EV_DIM + ii] = s_ev1[nb][ii] * (1.f + s_b[nb][seg]);
    }
}

// ---------------------------------------------------------------------------
extern "C" void kernel_launch(void* const* d_in, const int* in_sizes, int n_in,
                              void* d_out, int out_size, void* d_ws, size_t ws_size,
                              hipStream_t stream)
{
    const float* inv_feat  = (const float*)d_in[0];
    const float* ev_feat   = (const float*)d_in[1];
    const float* rbf       = (const float*)d_in[2];
    const float* sh_vec    = (const float*)d_in[3];
    const float* cutoffs   = (const float*)d_in[4];
    const int*   senders   = (const int*)d_in[5];
    const int*   receivers = (const int*)d_in[6];
    const float* Wq_inv = (const float*)d_in[7];
    const float* Wk_inv = (const float*)d_in[8];
    const float* Wv_inv = (const float*)d_in[9];
    const float* Wq_ev  = (const float*)d_in[10];
    const float* Wk_ev  = (const float*)d_in[11];
    const float* fi_rW1 = (const float*)d_in[12];
    const float* fi_rb1 = (const float*)d_in[13];
    const float* fi_rW2 = (const float*)d_in[14];
    const float* fi_rb2 = (const float*)d_in[15];
    const float* fi_eW1 = (const float*)d_in[16];
    const float* fi_eb1 = (const float*)d_in[17];
    const float* fi_eW2 = (const float*)d_in[18];
    const float* fi_eb2 = (const float*)d_in[19];
    const float* fe_rW1 = (const float*)d_in[20];
    const float* fe_rb1 = (const float*)d_in[21];
    const float* fe_rW2 = (const float*)d_in[22];
    const float* fe_rb2 = (const float*)d_in[23];
    const float* fe_eW1 = (const float*)d_in[24];
    const float* fe_eb1 = (const float*)d_in[25];
    const float* fe_eW2 = (const float*)d_in[26];
    const float* fe_eb2 = (const float*)d_in[27];
    const float* W_int  = (const float*)d_in[28];
    const float* b_int  = (const float*)d_in[29];

    const size_t NF = (size_t)N_NODES * F_DIM;
    const size_t NE = (size_t)N_NODES * EV_DIM;
    float* ws    = (float*)d_ws;
    float* a_inv = ws;                                  // NF f32
    float* a_ev  = ws + NF;                             // NE f32
    float* galpha = a_ev + NE;                          // E*8 f32
    int*   perm   = (int*)(galpha + (size_t)N_EDGES * 8);
    int*   gsnd   = perm + N_EDGES;
    int*   cnt    = gsnd + N_EDGES;
    int*   off    = cnt + N_NODES;
    int*   cursor = off + (N_NODES + 4);
    unsigned short* Bfrag  = (unsigned short*)(cursor + N_NODES);
    float*          biasC  = (float*)(Bfrag + 55296);
    unsigned short* B1frag = (unsigned short*)(biasC + 288);
    float*          biasB1 = (float*)(B1frag + 12288);
    unsigned short* Bnp    = (unsigned short*)(biasB1 + 384);
    int* tsum  = (int*)(Bnp + 55296);
    int* tbase = tsum + 64;
    unsigned short* q_inv = (unsigned short*)(tbase + 64);  // NF bf16 each
    unsigned short* k_inv = q_inv + NF;
    unsigned short* q_ev  = k_inv + NF;
    unsigned short* k_ev  = q_ev + NF;
    unsigned short* v_bf  = k_ev + NF;
    unsigned short* Wfrag_int = v_bf + NF;               // 23040 bf16

    float* out0 = (float*)d_out;
    float* out1 = out0 + NF;

    hipMemsetAsync(cnt, 0, N_NODES * sizeof(int), stream);
    hist_kernel<<<(N_EDGES + 255) / 256, 256, 0, stream>>>(receivers, cnt);
    scan_tile_sum<<<49, 1024, 0, stream>>>(cnt, tsum);
    scan_base<<<1, 64, 0, stream>>>(tsum, tbase);
    scan_tile<<<49, 1024, 0, stream>>>(cnt, tbase, off, cursor);
    scatter_kernel<<<(N_EDGES + 255) / 256, 256, 0, stream>>>(receivers, cursor, perm);

    prep_w2_kernel<<<39, 256, 0, stream>>>(
        fi_rW2, fi_eW2, fe_rW2, fe_eW2,
        fi_rb2, fi_eb2, fe_rb2, fe_eb2, W_int, Bfrag, biasC, Wfrag_int);

    prep_aux_kernel<<<35, 256, 0, stream>>>(
        fi_rW1, fe_rW1, fi_rb1, fi_eb1, fe_rb1, fe_eb1,
        Wq_inv, Wk_inv, Wv_inv, Wq_ev, Wk_ev,
        B1frag, biasB1, Bnp);

    node_proj_kernel<<<(N_NODES + NPB - 1) / NPB, 256, 0, stream>>>(
        inv_feat, Bnp, q_inv, k_inv, v_bf, q_ev, k_ev);

    edge_alpha_kernel<<<N_EDGES / TE, 256, 0, stream>>>(
        ev_feat, rbf, cutoffs, senders, receivers, perm,
        fi_eW1, fe_eW1, B1frag, biasB1, Bfrag, biasC,
        q_inv, k_inv, q_ev, k_ev,
        galpha, gsnd);

    gather_kernel<<<N_NODES / 4, 256, 0, stream>>>(
        v_bf, sh_vec, galpha, gsnd, perm, off, a_inv, a_ev);

    epilogue_kernel<<<N_NODES / 16, 256, 0, stream>>>(
        inv_feat, ev_feat, a_inv, a_ev, Wfrag_int, b_int, out0, out1);
}